// Round 11
// baseline (356.835 us; speedup 1.0000x reference)
//
#include <hip/hip_runtime.h>
#include <math.h>

// Problem constants
#define D_MODEL 2048
#define N_HEADS 16
#define N_KV    4
#define DH      128
#define QKV_DIM 3072   // 2048 + 2*4*128
#define TT      2048   // T
#define BB      2      // B
#define ROWS    (BB*TT)  // 4096

// Packed QKV layout in d_out (u16 offsets). Written by gemm1 epilogue:
//   Qp[b][h][t][d]   : ((b*16+h)*2048 + t)*128 + d          @ 0
//   Kp[g][t][d]      : (g*2048 + t)*128 + d                 @ 8,388,608   (g=b*4+hk)
//   Vt[g][d][t]      : (g*128 + d)*2048 + t                 @ 10,485,760  (V pre-transposed)
// Total 12,582,912 u16 = 25,165,824 B (same region/lifetime as old QKV).
#define QP_OFF 0u
#define KP_OFF 8388608u
#define VT_OFF 10485760u

typedef unsigned short u16;
typedef short short8 __attribute__((ext_vector_type(8)));
typedef short short4v __attribute__((ext_vector_type(4)));
typedef float float4v __attribute__((ext_vector_type(4)));

__device__ inline u16 f2b(float f) {
    union { float f; unsigned u; } v; v.f = f;
    unsigned r = v.u + 0x7FFF + ((v.u >> 16) & 1);
    return (u16)(r >> 16);
}

// async global->LDS DMA, 16 bytes/lane. LDS dest = wave-uniform base + lane*16.
__device__ inline void async16(const void* g, void* l) {
    __builtin_amdgcn_global_load_lds(
        (const __attribute__((address_space(1))) void*)g,
        (__attribute__((address_space(3))) void*)l, 16, 0, 0);
}

// ---------------------------------------------------------------------------
// 32x32 transpose tile body (shared by prep/attn_wo fused kernels).
// dst[c][r] = bf16(src[r][c + col0]). 256 threads. tile = u16[32][33].
__device__ inline void transpose_tile(const float* __restrict__ src,
                                      u16* __restrict__ dst,
                                      int R, int C, int col0,
                                      int bx, int by, u16* tile) {
    int bc = bx * 32, br = by * 32;
    int tx = threadIdx.x & 31, ty = threadIdx.x >> 5;   // ty 0..7
    for (int i = ty; i < 32; i += 8)
        tile[i * 33 + tx] = f2b(src[(size_t)(br + i) * C + col0 + bc + tx]);
    __syncthreads();
    for (int i = ty; i < 32; i += 8)
        dst[(size_t)(bc + i) * R + br + tx] = tile[tx * 33 + i];
}

// ---------------------------------------------------------------------------
// Fused preprocessing (saves 2 launch gaps):
//   blocks [0, 8192)        : x fp32 -> xb bf16 (vectorized convert)
//   blocks [8192, 12288)    : Wqkv^T cols 0..2047  -> WqkvTA
//   blocks [12288, 14336)   : Wqkv^T cols 2048..3071 -> WqkvTB
__global__ __launch_bounds__(256) void prep_kernel(
    const float* __restrict__ x, u16* __restrict__ xb,
    const float* __restrict__ Wqkv, u16* __restrict__ WA, u16* __restrict__ WB) {
    __shared__ __align__(16) u16 tile[32 * 33];
    int bid = blockIdx.x;
    if (bid < 8192) {
        size_t i = (size_t)bid * 256 + threadIdx.x;
        float4v a = *(const float4v*)(x + i * 4);
        short4v p;
        p[0] = (short)f2b(a[0]); p[1] = (short)f2b(a[1]);
        p[2] = (short)f2b(a[2]); p[3] = (short)f2b(a[3]);
        *(short4v*)(xb + i * 4) = p;
    } else if (bid < 12288) {
        int t = bid - 8192;                     // dim3(64,64)
        transpose_tile(Wqkv, WA, D_MODEL, QKV_DIM, 0, t & 63, t >> 6, tile);
    } else {
        int t = bid - 12288;                    // dim3(32,64)
        transpose_tile(Wqkv, WB, D_MODEL, QKV_DIM, 2048, t & 31, t >> 5, tile);
    }
}

// ---------------------------------------------------------------------------
// m97-style async GEMM v4: C[M,N] = A[M,K] @ Bt[N,K]^T, bf16 in, fp32 accum.
// vs v3 (round 10: 91.3us, conflicts=0, MfmaUtil 23, Occupancy 27%):
//  TILE 128x128 -> 128x64. Diagnosis: the gemm is TLP-starved by its GRID —
//  768 blocks = 3/CU while LDS(16K)/VGPR(84) allow 6+. Per-iter: 80 cyc MFMA
//  vs ~350 cyc wall => ~270 cyc latency covered 3-deep only. Halving BN
//  doubles the grid (gemm1 1536 blocks = 6/CU, gemm2 1024 = 4/CU), LDS
//  12 KB/block, VGPR ~70. Staging instrs/FLOP +33% but staging is latency-
//  hidden (HBM 15%). Rounds 8/9 proved residency is the binding constraint;
//  this is the first change that RAISES it.
// Chunk-XOR swizzle unchanged (proven 0-conflict): LDS[row][c16] =
//  G[row][c16 ^ ((row>>1)&3)] via pre-swizzled DMA source (rule #21); all
//  slab bases are multiples of 16 rows so source key (lane>>3)&3 and read
//  key (l16>>1)&3 are unchanged.
// B^T split across two buffers at N-row `nsplit` (workspace tetris).
// ROPE: fused rotary on cols < 2560 (fast hw trig).
// !F32OUT (gemm1): writes the PACKED QKV layout (Qp/Kp/Vt).
template<bool F32OUT, bool ROPE>
__global__ __launch_bounds__(256) void gemm_bt_async(
    const u16* __restrict__ A, const u16* __restrict__ Bt1, const u16* __restrict__ Bt2,
    int nsplit, void* __restrict__ Cv, int M, int N, int K, const int* __restrict__ sp) {
    __shared__ __align__(16) u16 As[128 * 32];   // 8 KB
    __shared__ __align__(16) u16 Bs[64 * 32];    // 4 KB
    const int tid = threadIdx.x;
    const int wave = tid >> 6, lane = tid & 63;
    const int quad = lane >> 4, l16 = lane & 15;
    const int bm = blockIdx.y * 128, bn = blockIdx.x * 64;
    const int wm = (wave >> 1) * 64, wn = (wave & 1) * 32;
    const int srow = wave * 32 + (lane >> 2);    // A staging rows
    const int brow = wave * 16 + (lane >> 2);    // B staging rows
    // source chunk pre-swizzle: row-in-slab = lane>>2, key = (row>>1)&3
    // = (lane>>3)&3 (slab bases are multiples of 16 -> key wave-uniform).
    const int scol = ((lane & 3) ^ ((lane >> 3) & 3)) * 8;
    const int rsw = (l16 >> 1) & 3;             // read-side XOR key
    const u16* Bt = (bn < nsplit) ? (Bt1 + (size_t)bn * K)
                                  : (Bt2 + (size_t)(bn - nsplit) * K);

    float4v acc[4][2] = {};

    for (int k0 = 0; k0 < K; k0 += 32) {
        async16(A + (size_t)(bm + srow) * K + k0 + scol, (char*)As + wave * 2048);
        async16(A + (size_t)(bm + srow + 16) * K + k0 + scol, (char*)As + wave * 2048 + 1024);
        async16(Bt + (size_t)brow * K + k0 + scol, (char*)Bs + wave * 1024);
        __syncthreads();
        short8 af[4], bf[2];
#pragma unroll
        for (int i = 0; i < 4; i++)
            af[i] = *(const short8*)(As + (wm + i * 16 + l16) * 32
                                     + ((quad ^ rsw) * 8));
#pragma unroll
        for (int j = 0; j < 2; j++)
            bf[j] = *(const short8*)(Bs + (wn + j * 16 + l16) * 32
                                     + ((quad ^ rsw) * 8));
#pragma unroll
        for (int i = 0; i < 4; i++)
#pragma unroll
            for (int j = 0; j < 2; j++)
                acc[i][j] = __builtin_amdgcn_mfma_f32_16x16x32_bf16(af[i], bf[j], acc[i][j], 0, 0, 0);
        __syncthreads();
    }
    const int sp0 = ROPE ? *sp : 0;
    // epilogue: C/D layout col=lane&15, row=quad*4+reg (m89/m91-verified).
#pragma unroll
    for (int j = 0; j < 2; j++) {
        int col = bn + wn + j * 16 + l16;
        bool do_rope = ROPE && (col < 2560);
        float inv = 0.f;
        if (do_rope) inv = __expf(-0.14391156816f * (float)((col & 127) >> 1));
#pragma unroll
        for (int i = 0; i < 4; i++) {
            int row0 = bm + wm + i * 16 + quad * 4;
#pragma unroll
            for (int r = 0; r < 4; r++) {
                float v = acc[i][j][r];
                if (do_rope) {
                    float partner = __shfl_xor(v, 1, 64);
                    float ang = (float)(sp0 + ((row0 + r) & (TT - 1))) * inv;
                    float c = __cosf(ang), s = __sinf(ang);
                    v = (col & 1) ? (partner * s + v * c)
                                  : (v * c - partner * s);
                }
                if (F32OUT) {
                    ((float*)Cv)[(size_t)(row0 + r) * N + col] = v;
                } else {
                    // packed QKV store (region is wave-uniform per j-block)
                    int rw = row0 + r;
                    int bb = rw >> 11, t = rw & 2047;
                    size_t addr;
                    if (col < 2048)
                        addr = QP_OFF + (size_t)(bb * 16 + (col >> 7)) * 262144
                             + (size_t)t * 128 + (col & 127);
                    else if (col < 2560)
                        addr = KP_OFF + (size_t)(bb * 4 + ((col - 2048) >> 7)) * 262144
                             + (size_t)t * 128 + (col & 127);
                    else
                        addr = VT_OFF + (size_t)(bb * 4 + ((col - 2560) >> 7)) * 262144
                             + (size_t)(col & 127) * 2048 + t;
                    ((u16*)Cv)[addr] = f2b(v);
                }
            }
        }
    }
}

// ---------------------------------------------------------------------------
// Fused flash-attention + Wo^T transpose.
//   blocks [0, 512)     : flash attention v10 (unchanged)
//   blocks [512, 4608)  : Wo^T transpose -> WoT
__global__ __launch_bounds__(256, 2) void attn_wo_kernel(
    const u16* __restrict__ qkv, u16* __restrict__ y,
    const float* __restrict__ Wo, u16* __restrict__ WoT) {
    __shared__ __align__(16) u16 Ks[2][32 * 128];   // 2 x 8192 B
    __shared__ __align__(16) u16 Vs[2][128 * 32];   // 2 x 8192 B (V^T: d rows)
    __shared__ __align__(16) u16 Ps[4][32 * 32];    // 8192 B   (total 40960)

    if (blockIdx.x >= 512) {                        // Wo^T transpose blocks
        int t = blockIdx.x - 512;                   // dim3(64,64)
        transpose_tile(Wo, WoT, D_MODEL, D_MODEL, 0, t & 63, t >> 6, (u16*)Ks[0]);
        return;
    }

    const int tid = threadIdx.x;
    const int wave = tid >> 6, lane = tid & 63;
    const int quad = lane >> 4, l16 = lane & 15;
    const int bx = blockIdx.x;
    const int xg = bx & 7;             // XCD group = (b, hk)
    const int b = xg >> 2, hk = xg & 3;
    const int jj = bx >> 3;            // 0..63 within group = XCD stream pos
    // dual-pairing-robust balance map (jj^1 and jj^32 both flip parity only)
    const int h = hk * 4 + 2 * ((jj >> 2) & 1) + (jj & 1);
    const int u = ((jj >> 1) & 1) | (((jj >> 3) & 1) << 1) | (((jj >> 4) & 1) << 2);
    const int p = ((jj >> 5) ^ jj) & 1;
    const int qt = p ? (15 - u) : u;
    const int g = b * 4 + hk;
    const float scale = 0.08838834764831845f;  // 1/sqrt(128)

    // Q fragments in registers (reused every kv-tile): 2 row-groups of 16
    const int wq0 = qt * 128 + wave * 32;
    const u16* qbase = qkv + QP_OFF + (size_t)(b * 16 + h) * 262144;
    short8 qf[2][4];
#pragma unroll
    for (int gi = 0; gi < 2; gi++) {
        const u16* qrow = qbase + (size_t)(wq0 + gi * 16 + l16) * 128;
#pragma unroll
        for (int d = 0; d < 4; d++)
            qf[gi][d] = *(const short8*)(qrow + d * 32 + quad * 8);
    }

    // Oacc[gi][0..7]: O tiles (2 x 16 x 128). Ol[gi]: row-sum l via ones MFMA.
    float4v Oacc[2][8] = {};
    float4v Ol[2] = {};
    const short8 ONES = {(short)0x3F80, (short)0x3F80, (short)0x3F80, (short)0x3F80,
                         (short)0x3F80, (short)0x3F80, (short)0x3F80, (short)0x3F80};

    const int ktmax = 4 * qt + 3;      // kv tiles - 1 (32 kv rows per tile)

    size_t kg[2];
#pragma unroll
    for (int si = 0; si < 2; si++) {
        int kr = wave * 8 + si * 4 + quad;
        kg[si] = (size_t)kr * 128 + (size_t)((l16 ^ (kr & 7)) * 8);
    }
    size_t vg[2];
#pragma unroll
    for (int si = 0; si < 2; si++) {
        int vr = wave * 32 + si * 16 + (lane >> 2);
        vg[si] = (size_t)vr * 2048 + (size_t)((((lane & 3) ^ ((lane >> 3) & 3)) * 8));
    }
    const u16* Kb = qkv + KP_OFF + (size_t)g * 262144;
    const u16* Vb = qkv + VT_OFF + (size_t)g * 262144;

    // kt=0 prefetch (both K and V^T via DMA)
#pragma unroll
    for (int si = 0; si < 2; si++)
        async16(Kb + kg[si], (char*)Ks[0] + wave * 2048 + si * 1024);
#pragma unroll
    for (int si = 0; si < 2; si++)
        async16(Vb + vg[si], (char*)Vs[0] + wave * 2048 + si * 1024);

    for (int kt = 0; kt <= ktmax; kt++) {
        const int cur = kt & 1;
        __syncthreads();   // vmcnt(0)+barrier: DMA for buf[cur] complete
        if (kt < ktmax) {  // prefetch next tile into buf[cur^1]
#pragma unroll
            for (int si = 0; si < 2; si++)
                async16(Kb + (size_t)(kt + 1) * 4096 + kg[si],
                        (char*)Ks[cur ^ 1] + wave * 2048 + si * 1024);
#pragma unroll
            for (int si = 0; si < 2; si++)
                async16(Vb + (size_t)(kt + 1) * 32 + vg[si],
                        (char*)Vs[cur ^ 1] + wave * 2048 + si * 1024);
        }
        const u16* Kcur = Ks[cur];
        const u16* Vcur = Vs[cur];

        float4v S[2][2] = {};
#pragma unroll
        for (int d = 0; d < 4; d++) {
#pragma unroll
            for (int j = 0; j < 2; j++) {
                short8 bk = *(const short8*)(Kcur + (j * 16 + l16) * 128
                                             + (((d * 4 + quad) ^ (l16 & 7)) * 8));
#pragma unroll
                for (int gi = 0; gi < 2; gi++)
                    S[gi][j] = __builtin_amdgcn_mfma_f32_16x16x32_bf16(qf[gi][d], bk, S[gi][j], 0, 0, 0);
            }
        }
        const int kvb = kt * 32 + l16;
        const bool diag = (kt * 32 + 31 > wq0);
#pragma unroll
        for (int gi = 0; gi < 2; gi++) {
            const int qbq = wq0 + gi * 16 + quad * 4;
#pragma unroll
            for (int j = 0; j < 2; j++)
#pragma unroll
                for (int r = 0; r < 4; r++) {
                    bool masked = diag && (kvb + j * 16 > qbq + r);
                    float pv = masked ? 0.f : __expf(S[gi][j][r] * scale);
                    int rq = gi * 16 + quad * 4 + r;
                    int ch = (j * 2 + (l16 >> 3)) ^ ((rq >> 1) & 3);
                    Ps[wave][rq * 32 + ch * 8 + (l16 & 7)] = f2b(pv);
                }
        }
        __asm__ volatile("s_waitcnt lgkmcnt(0)" ::: "memory");
        short8 ap[2];
#pragma unroll
        for (int gi = 0; gi < 2; gi++) {
            int rq = gi * 16 + l16;
            ap[gi] = *(const short8*)(Ps[wave] + rq * 32
                                      + ((quad ^ ((l16 >> 1) & 3)) * 8));
        }
#pragma unroll
        for (int dt = 0; dt < 8; dt++) {
            short8 bv = *(const short8*)(Vcur + (dt * 16 + l16) * 32
                                         + ((quad ^ ((l16 >> 1) & 3)) * 8));
#pragma unroll
            for (int gi = 0; gi < 2; gi++)
                Oacc[gi][dt] = __builtin_amdgcn_mfma_f32_16x16x32_bf16(ap[gi], bv, Oacc[gi][dt], 0, 0, 0);
        }
#pragma unroll
        for (int gi = 0; gi < 2; gi++)
            Ol[gi] = __builtin_amdgcn_mfma_f32_16x16x32_bf16(ap[gi], ONES, Ol[gi], 0, 0, 0);
    }
#pragma unroll
    for (int gi = 0; gi < 2; gi++)
#pragma unroll
        for (int dt = 0; dt < 8; dt++)
#pragma unroll
            for (int r = 0; r < 4; r++) {
                float v = Oacc[gi][dt][r] / Ol[gi][r];
                y[(size_t)(b * TT + wq0 + gi * 16 + quad * 4 + r) * D_MODEL
                  + h * 128 + dt * 16 + l16] = f2b(v);
            }
}

// ---------------------------------------------------------------------------
// Memory plan (ws use = 25,165,824 B, proven available; inputs/out fp32):
//   ws[0, 16.78M):      xb (phases 1-2) -> Y (attn -> gemm2)
//   ws[16.78M, 25.17M): WqkvT rows 0..2047 (gemm1) -> WoT (gemm2)
//   d_out[0, 25.17M):   packed Qp/Kp/Vt bf16 (gemm1 -> attn) -> final fp32 out
//   d_out[25.17M, 33.55M): WqkvT rows 2048..3071 (gemm1 only; dead after)
// Launches: 4 — prep, gemm1 (128x64 swizzled m97), attn+WoT, gemm2 (same).
extern "C" void kernel_launch(void* const* d_in, const int* in_sizes, int n_in,
                              void* d_out, int out_size, void* d_ws, size_t ws_size,
                              hipStream_t stream) {
    const float* x    = (const float*)d_in[0];   // 4096 x 2048 fp32
    const float* Wqkv = (const float*)d_in[1];   // 2048 x 3072 fp32
    const float* Wo   = (const float*)d_in[2];   // 2048 x 2048 fp32
    const int*   sp   = (const int*)d_in[3];

    char* ws = (char*)d_ws;
    char* dob = (char*)d_out;
    u16*   xb     = (u16*)ws;                    // 4096x2048 bf16
    u16*   Y      = (u16*)ws;                    //    (after gemm1: attn output)
    u16*   WqkvTA = (u16*)(ws + 16777216);       // N-rows 0..2047 of Wqkv^T
    u16*   WoT    = (u16*)(ws + 16777216);       //    (after gemm1)
    u16*   QKVp   = (u16*)d_out;                 // packed Qp/Kp/Vt bf16
    u16*   WqkvTB = (u16*)(dob + 25165824);      // N-rows 2048..3071 of Wqkv^T
    float* out    = (float*)d_out;

    // 1. fused prep: x->bf16 + Wqkv^T (both halves)
    prep_kernel<<<14336, 256, 0, stream>>>(x, xb, Wqkv, WqkvTA, WqkvTB);
    // 2. packed QKV = x @ Wqkv with fused RoPE (128x64 swizzled m97, 6 blk/CU)
    gemm_bt_async<false, true><<<dim3(QKV_DIM / 64, ROWS / 128), 256, 0, stream>>>(
        xb, WqkvTA, WqkvTB, 2048, QKVp, ROWS, QKV_DIM, D_MODEL, sp);
    // 3. fused flash attention (-> Y, overwrites xb) + Wo^T (-> dead WqkvTA)
    attn_wo_kernel<<<4608, 256, 0, stream>>>(QKVp, Y, Wo, WoT);
    // 4. out = Y @ Wo -> fp32 (overwrites packed QKV + WqkvTB, dead)
    gemm_bt_async<true, false><<<dim3(D_MODEL / 64, ROWS / 128), 256, 0, stream>>>(
        Y, WoT, WoT, D_MODEL, out, ROWS, D_MODEL, D_MODEL, sp);
}

// Round 12
// 337.430 us; speedup vs baseline: 1.0575x; 1.0575x over previous
//
#include <hip/hip_runtime.h>
#include <math.h>

// Problem constants
#define D_MODEL 2048
#define N_HEADS 16
#define N_KV    4
#define DH      128
#define QKV_DIM 3072   // 2048 + 2*4*128
#define TT      2048   // T
#define BB      2      // B
#define ROWS    (BB*TT)  // 4096

// Packed QKV layout in d_out (u16 offsets). Written by gemm1 epilogue:
//   Qp[b][h][t][d]   : ((b*16+h)*2048 + t)*128 + d          @ 0
//   Kp[g][t][d]      : (g*2048 + t)*128 + d                 @ 8,388,608   (g=b*4+hk)
//   Vt[g][d][t]      : (g*128 + d)*2048 + t                 @ 10,485,760  (V pre-transposed)
// Total 12,582,912 u16 = 25,165,824 B (same region/lifetime as old QKV).
#define QP_OFF 0u
#define KP_OFF 8388608u
#define VT_OFF 10485760u

typedef unsigned short u16;
typedef short short8 __attribute__((ext_vector_type(8)));
typedef short short4v __attribute__((ext_vector_type(4)));
typedef float float4v __attribute__((ext_vector_type(4)));

__device__ inline u16 f2b(float f) {
    union { float f; unsigned u; } v; v.f = f;
    unsigned r = v.u + 0x7FFF + ((v.u >> 16) & 1);
    return (u16)(r >> 16);
}

// async global->LDS DMA, 16 bytes/lane. LDS dest = wave-uniform base + lane*16.
__device__ inline void async16(const void* g, void* l) {
    __builtin_amdgcn_global_load_lds(
        (const __attribute__((address_space(1))) void*)g,
        (__attribute__((address_space(3))) void*)l, 16, 0, 0);
}

// ---------------------------------------------------------------------------
// 32x32 transpose tile body (shared by prep/attn_wo fused kernels).
// dst[c][r] = bf16(src[r][c + col0]). 256 threads. tile = u16[32][33].
__device__ inline void transpose_tile(const float* __restrict__ src,
                                      u16* __restrict__ dst,
                                      int R, int C, int col0,
                                      int bx, int by, u16* tile) {
    int bc = bx * 32, br = by * 32;
    int tx = threadIdx.x & 31, ty = threadIdx.x >> 5;   // ty 0..7
    for (int i = ty; i < 32; i += 8)
        tile[i * 33 + tx] = f2b(src[(size_t)(br + i) * C + col0 + bc + tx]);
    __syncthreads();
    for (int i = ty; i < 32; i += 8)
        dst[(size_t)(bc + i) * R + br + tx] = tile[tx * 33 + i];
}

// ---------------------------------------------------------------------------
// Fused preprocessing (saves 2 launch gaps):
//   blocks [0, 8192)        : x fp32 -> xb bf16 (vectorized convert)
//   blocks [8192, 12288)    : Wqkv^T cols 0..2047  -> WqkvTA
//   blocks [12288, 14336)   : Wqkv^T cols 2048..3071 -> WqkvTB
__global__ __launch_bounds__(256) void prep_kernel(
    const float* __restrict__ x, u16* __restrict__ xb,
    const float* __restrict__ Wqkv, u16* __restrict__ WA, u16* __restrict__ WB) {
    __shared__ __align__(16) u16 tile[32 * 33];
    int bid = blockIdx.x;
    if (bid < 8192) {
        size_t i = (size_t)bid * 256 + threadIdx.x;
        float4v a = *(const float4v*)(x + i * 4);
        short4v p;
        p[0] = (short)f2b(a[0]); p[1] = (short)f2b(a[1]);
        p[2] = (short)f2b(a[2]); p[3] = (short)f2b(a[3]);
        *(short4v*)(xb + i * 4) = p;
    } else if (bid < 12288) {
        int t = bid - 8192;                     // dim3(64,64)
        transpose_tile(Wqkv, WA, D_MODEL, QKV_DIM, 0, t & 63, t >> 6, tile);
    } else {
        int t = bid - 12288;                    // dim3(32,64)
        transpose_tile(Wqkv, WB, D_MODEL, QKV_DIM, 2048, t & 31, t >> 5, tile);
    }
}

// ---------------------------------------------------------------------------
// m97-style async GEMM v5: C[M,N] = A[M,K] @ Bt[N,K]^T, bf16 in, fp32 accum.
// = round-10 config EXACTLY (128x128, BK=32, 16 KB LDS, chunk-XOR swizzle,
// 0 conflicts, 91.3us/gemm — the proven local optimum: 256^2-8ph, BK=64,
// and BN=64 all regressed −11/−13/−28us), plus ONE new occupancy-neutral
// lever: XCD-aware block swizzle (T1).
//   1D grid; hardware round-robins bid across the 8 XCDs (bid&7 = XCD).
//   wg = (bid&7)*(nwg/8) + (bid>>3); m-major within XCD -> each XCD owns a
//   contiguous N-chunk (gemm1: 3 N-tiles -> B working set 1.5 MB, resident
//   in its private 4 MB L2; gemm2: 2 N-tiles, 1 MB). Shorter load latency
//   for a latency-bound loop; FETCH was 2.4x ideal (71.8 vs ~30 MB).
//   Bijective: nwg % 8 == 0 (768, 512 — ERRATA #11 check).
// Chunk-XOR swizzle: LDS[row][c16] = G[row][c16 ^ ((row>>1)&3)] via
// pre-swizzled DMA source (rule #21), read back with the same XOR.
// B^T split across two buffers at N-row `nsplit` (workspace tetris).
// ROPE: fused rotary on cols < 2560 (fast hw trig).
// !F32OUT (gemm1): writes the PACKED QKV layout (Qp/Kp/Vt).
template<bool F32OUT, bool ROPE>
__global__ __launch_bounds__(256) void gemm_bt_async(
    const u16* __restrict__ A, const u16* __restrict__ Bt1, const u16* __restrict__ Bt2,
    int nsplit, void* __restrict__ Cv, int M, int N, int K, const int* __restrict__ sp) {
    __shared__ __align__(16) u16 As[128 * 32];   // 8 KB
    __shared__ __align__(16) u16 Bs[128 * 32];   // 8 KB
    const int tid = threadIdx.x;
    const int wave = tid >> 6, lane = tid & 63;
    const int quad = lane >> 4, l16 = lane & 15;
    // XCD swizzle: contiguous N-chunk per XCD, m-major inside the chunk.
    const int MT = M >> 7;
    const int nwg = MT * (N >> 7);
    const int bid = blockIdx.x;
    const int wg = (bid & 7) * (nwg >> 3) + (bid >> 3);
    const int bm = (wg % MT) * 128, bn = (wg / MT) * 128;
    const int wm = (wave >> 1) * 64, wn = (wave & 1) * 64;
    const int srow = wave * 32 + (lane >> 2);
    // source chunk pre-swizzle: row-in-slab = lane>>2, key = (row>>1)&3
    // = (lane>>3)&3 (slab bases are multiples of 16 -> key wave-uniform).
    const int scol = ((lane & 3) ^ ((lane >> 3) & 3)) * 8;
    const int rsw = (l16 >> 1) & 3;             // read-side XOR key
    const u16* Bt = (bn < nsplit) ? (Bt1 + (size_t)bn * K)
                                  : (Bt2 + (size_t)(bn - nsplit) * K);

    float4v acc[4][4] = {};

    for (int k0 = 0; k0 < K; k0 += 32) {
        async16(A + (size_t)(bm + srow) * K + k0 + scol, (char*)As + wave * 2048);
        async16(A + (size_t)(bm + srow + 16) * K + k0 + scol, (char*)As + wave * 2048 + 1024);
        async16(Bt + (size_t)srow * K + k0 + scol, (char*)Bs + wave * 2048);
        async16(Bt + (size_t)(srow + 16) * K + k0 + scol, (char*)Bs + wave * 2048 + 1024);
        __syncthreads();
        short8 af[4], bf[4];
#pragma unroll
        for (int i = 0; i < 4; i++)
            af[i] = *(const short8*)(As + (wm + i * 16 + l16) * 32
                                     + ((quad ^ rsw) * 8));
#pragma unroll
        for (int j = 0; j < 4; j++)
            bf[j] = *(const short8*)(Bs + (wn + j * 16 + l16) * 32
                                     + ((quad ^ rsw) * 8));
#pragma unroll
        for (int i = 0; i < 4; i++)
#pragma unroll
            for (int j = 0; j < 4; j++)
                acc[i][j] = __builtin_amdgcn_mfma_f32_16x16x32_bf16(af[i], bf[j], acc[i][j], 0, 0, 0);
        __syncthreads();
    }
    const int sp0 = ROPE ? *sp : 0;
    // epilogue: C/D layout col=lane&15, row=quad*4+reg (m89/m91-verified).
#pragma unroll
    for (int j = 0; j < 4; j++) {
        int col = bn + wn + j * 16 + l16;
        bool do_rope = ROPE && (col < 2560);
        float inv = 0.f;
        if (do_rope) inv = __expf(-0.14391156816f * (float)((col & 127) >> 1));
#pragma unroll
        for (int i = 0; i < 4; i++) {
            int row0 = bm + wm + i * 16 + quad * 4;
#pragma unroll
            for (int r = 0; r < 4; r++) {
                float v = acc[i][j][r];
                if (do_rope) {
                    float partner = __shfl_xor(v, 1, 64);
                    float ang = (float)(sp0 + ((row0 + r) & (TT - 1))) * inv;
                    float c = __cosf(ang), s = __sinf(ang);
                    v = (col & 1) ? (partner * s + v * c)
                                  : (v * c - partner * s);
                }
                if (F32OUT) {
                    ((float*)Cv)[(size_t)(row0 + r) * N + col] = v;
                } else {
                    // packed QKV store (region is wave-uniform per j-block)
                    int rw = row0 + r;
                    int bb = rw >> 11, t = rw & 2047;
                    size_t addr;
                    if (col < 2048)
                        addr = QP_OFF + (size_t)(bb * 16 + (col >> 7)) * 262144
                             + (size_t)t * 128 + (col & 127);
                    else if (col < 2560)
                        addr = KP_OFF + (size_t)(bb * 4 + ((col - 2048) >> 7)) * 262144
                             + (size_t)t * 128 + (col & 127);
                    else
                        addr = VT_OFF + (size_t)(bb * 4 + ((col - 2560) >> 7)) * 262144
                             + (size_t)(col & 127) * 2048 + t;
                    ((u16*)Cv)[addr] = f2b(v);
                }
            }
        }
    }
}

// ---------------------------------------------------------------------------
// Fused flash-attention + Wo^T transpose.
//   blocks [0, 512)     : flash attention v10 (unchanged)
//   blocks [512, 4608)  : Wo^T transpose -> WoT
__global__ __launch_bounds__(256, 2) void attn_wo_kernel(
    const u16* __restrict__ qkv, u16* __restrict__ y,
    const float* __restrict__ Wo, u16* __restrict__ WoT) {
    __shared__ __align__(16) u16 Ks[2][32 * 128];   // 2 x 8192 B
    __shared__ __align__(16) u16 Vs[2][128 * 32];   // 2 x 8192 B (V^T: d rows)
    __shared__ __align__(16) u16 Ps[4][32 * 32];    // 8192 B   (total 40960)

    if (blockIdx.x >= 512) {                        // Wo^T transpose blocks
        int t = blockIdx.x - 512;                   // dim3(64,64)
        transpose_tile(Wo, WoT, D_MODEL, D_MODEL, 0, t & 63, t >> 6, (u16*)Ks[0]);
        return;
    }

    const int tid = threadIdx.x;
    const int wave = tid >> 6, lane = tid & 63;
    const int quad = lane >> 4, l16 = lane & 15;
    const int bx = blockIdx.x;
    const int xg = bx & 7;             // XCD group = (b, hk)
    const int b = xg >> 2, hk = xg & 3;
    const int jj = bx >> 3;            // 0..63 within group = XCD stream pos
    // dual-pairing-robust balance map (jj^1 and jj^32 both flip parity only)
    const int h = hk * 4 + 2 * ((jj >> 2) & 1) + (jj & 1);
    const int u = ((jj >> 1) & 1) | (((jj >> 3) & 1) << 1) | (((jj >> 4) & 1) << 2);
    const int p = ((jj >> 5) ^ jj) & 1;
    const int qt = p ? (15 - u) : u;
    const int g = b * 4 + hk;
    const float scale = 0.08838834764831845f;  // 1/sqrt(128)

    // Q fragments in registers (reused every kv-tile): 2 row-groups of 16
    const int wq0 = qt * 128 + wave * 32;
    const u16* qbase = qkv + QP_OFF + (size_t)(b * 16 + h) * 262144;
    short8 qf[2][4];
#pragma unroll
    for (int gi = 0; gi < 2; gi++) {
        const u16* qrow = qbase + (size_t)(wq0 + gi * 16 + l16) * 128;
#pragma unroll
        for (int d = 0; d < 4; d++)
            qf[gi][d] = *(const short8*)(qrow + d * 32 + quad * 8);
    }

    // Oacc[gi][0..7]: O tiles (2 x 16 x 128). Ol[gi]: row-sum l via ones MFMA.
    float4v Oacc[2][8] = {};
    float4v Ol[2] = {};
    const short8 ONES = {(short)0x3F80, (short)0x3F80, (short)0x3F80, (short)0x3F80,
                         (short)0x3F80, (short)0x3F80, (short)0x3F80, (short)0x3F80};

    const int ktmax = 4 * qt + 3;      // kv tiles - 1 (32 kv rows per tile)

    size_t kg[2];
#pragma unroll
    for (int si = 0; si < 2; si++) {
        int kr = wave * 8 + si * 4 + quad;
        kg[si] = (size_t)kr * 128 + (size_t)((l16 ^ (kr & 7)) * 8);
    }
    size_t vg[2];
#pragma unroll
    for (int si = 0; si < 2; si++) {
        int vr = wave * 32 + si * 16 + (lane >> 2);
        vg[si] = (size_t)vr * 2048 + (size_t)((((lane & 3) ^ ((lane >> 3) & 3)) * 8));
    }
    const u16* Kb = qkv + KP_OFF + (size_t)g * 262144;
    const u16* Vb = qkv + VT_OFF + (size_t)g * 262144;

    // kt=0 prefetch (both K and V^T via DMA)
#pragma unroll
    for (int si = 0; si < 2; si++)
        async16(Kb + kg[si], (char*)Ks[0] + wave * 2048 + si * 1024);
#pragma unroll
    for (int si = 0; si < 2; si++)
        async16(Vb + vg[si], (char*)Vs[0] + wave * 2048 + si * 1024);

    for (int kt = 0; kt <= ktmax; kt++) {
        const int cur = kt & 1;
        __syncthreads();   // vmcnt(0)+barrier: DMA for buf[cur] complete
        if (kt < ktmax) {  // prefetch next tile into buf[cur^1]
#pragma unroll
            for (int si = 0; si < 2; si++)
                async16(Kb + (size_t)(kt + 1) * 4096 + kg[si],
                        (char*)Ks[cur ^ 1] + wave * 2048 + si * 1024);
#pragma unroll
            for (int si = 0; si < 2; si++)
                async16(Vb + (size_t)(kt + 1) * 32 + vg[si],
                        (char*)Vs[cur ^ 1] + wave * 2048 + si * 1024);
        }
        const u16* Kcur = Ks[cur];
        const u16* Vcur = Vs[cur];

        float4v S[2][2] = {};
#pragma unroll
        for (int d = 0; d < 4; d++) {
#pragma unroll
            for (int j = 0; j < 2; j++) {
                short8 bk = *(const short8*)(Kcur + (j * 16 + l16) * 128
                                             + (((d * 4 + quad) ^ (l16 & 7)) * 8));
#pragma unroll
                for (int gi = 0; gi < 2; gi++)
                    S[gi][j] = __builtin_amdgcn_mfma_f32_16x16x32_bf16(qf[gi][d], bk, S[gi][j], 0, 0, 0);
            }
        }
        const int kvb = kt * 32 + l16;
        const bool diag = (kt * 32 + 31 > wq0);
#pragma unroll
        for (int gi = 0; gi < 2; gi++) {
            const int qbq = wq0 + gi * 16 + quad * 4;
#pragma unroll
            for (int j = 0; j < 2; j++)
#pragma unroll
                for (int r = 0; r < 4; r++) {
                    bool masked = diag && (kvb + j * 16 > qbq + r);
                    float pv = masked ? 0.f : __expf(S[gi][j][r] * scale);
                    int rq = gi * 16 + quad * 4 + r;
                    int ch = (j * 2 + (l16 >> 3)) ^ ((rq >> 1) & 3);
                    Ps[wave][rq * 32 + ch * 8 + (l16 & 7)] = f2b(pv);
                }
        }
        __asm__ volatile("s_waitcnt lgkmcnt(0)" ::: "memory");
        short8 ap[2];
#pragma unroll
        for (int gi = 0; gi < 2; gi++) {
            int rq = gi * 16 + l16;
            ap[gi] = *(const short8*)(Ps[wave] + rq * 32
                                      + ((quad ^ ((l16 >> 1) & 3)) * 8));
        }
#pragma unroll
        for (int dt = 0; dt < 8; dt++) {
            short8 bv = *(const short8*)(Vcur + (dt * 16 + l16) * 32
                                         + ((quad ^ ((l16 >> 1) & 3)) * 8));
#pragma unroll
            for (int gi = 0; gi < 2; gi++)
                Oacc[gi][dt] = __builtin_amdgcn_mfma_f32_16x16x32_bf16(ap[gi], bv, Oacc[gi][dt], 0, 0, 0);
        }
#pragma unroll
        for (int gi = 0; gi < 2; gi++)
            Ol[gi] = __builtin_amdgcn_mfma_f32_16x16x32_bf16(ap[gi], ONES, Ol[gi], 0, 0, 0);
    }
#pragma unroll
    for (int gi = 0; gi < 2; gi++)
#pragma unroll
        for (int dt = 0; dt < 8; dt++)
#pragma unroll
            for (int r = 0; r < 4; r++) {
                float v = Oacc[gi][dt][r] / Ol[gi][r];
                y[(size_t)(b * TT + wq0 + gi * 16 + quad * 4 + r) * D_MODEL
                  + h * 128 + dt * 16 + l16] = f2b(v);
            }
}

// ---------------------------------------------------------------------------
// Memory plan (ws use = 25,165,824 B, proven available; inputs/out fp32):
//   ws[0, 16.78M):      xb (phases 1-2) -> Y (attn -> gemm2)
//   ws[16.78M, 25.17M): WqkvT rows 0..2047 (gemm1) -> WoT (gemm2)
//   d_out[0, 25.17M):   packed Qp/Kp/Vt bf16 (gemm1 -> attn) -> final fp32 out
//   d_out[25.17M, 33.55M): WqkvT rows 2048..3071 (gemm1 only; dead after)
// Launches: 4 — prep, gemm1 (128^2 swizzled m97 + XCD swz), attn+WoT, gemm2.
extern "C" void kernel_launch(void* const* d_in, const int* in_sizes, int n_in,
                              void* d_out, int out_size, void* d_ws, size_t ws_size,
                              hipStream_t stream) {
    const float* x    = (const float*)d_in[0];   // 4096 x 2048 fp32
    const float* Wqkv = (const float*)d_in[1];   // 2048 x 3072 fp32
    const float* Wo   = (const float*)d_in[2];   // 2048 x 2048 fp32
    const int*   sp   = (const int*)d_in[3];

    char* ws = (char*)d_ws;
    char* dob = (char*)d_out;
    u16*   xb     = (u16*)ws;                    // 4096x2048 bf16
    u16*   Y      = (u16*)ws;                    //    (after gemm1: attn output)
    u16*   WqkvTA = (u16*)(ws + 16777216);       // N-rows 0..2047 of Wqkv^T
    u16*   WoT    = (u16*)(ws + 16777216);       //    (after gemm1)
    u16*   QKVp   = (u16*)d_out;                 // packed Qp/Kp/Vt bf16
    u16*   WqkvTB = (u16*)(dob + 25165824);      // N-rows 2048..3071 of Wqkv^T
    float* out    = (float*)d_out;

    // 1. fused prep: x->bf16 + Wqkv^T (both halves)
    prep_kernel<<<14336, 256, 0, stream>>>(x, xb, Wqkv, WqkvTA, WqkvTB);
    // 2. packed QKV = x @ Wqkv with fused RoPE (128^2 swizzled m97, XCD swz)
    gemm_bt_async<false, true><<<768, 256, 0, stream>>>(
        xb, WqkvTA, WqkvTB, 2048, QKVp, ROWS, QKV_DIM, D_MODEL, sp);
    // 3. fused flash attention (-> Y, overwrites xb) + Wo^T (-> dead WqkvTA)
    attn_wo_kernel<<<4608, 256, 0, stream>>>(QKVp, Y, Wo, WoT);
    // 4. out = Y @ Wo -> fp32 (overwrites packed QKV + WqkvTB, dead)
    gemm_bt_async<true, false><<<512, 256, 0, stream>>>(
        Y, WoT, WoT, D_MODEL, out, ROWS, D_MODEL, D_MODEL, sp);
}